// Round 4
// baseline (1427.516 us; speedup 1.0000x reference)
//
#include <hip/hip_runtime.h>
#include <cstdint>
#include <cstddef>

#define T_DIM 4096
#define H_DIM 4096
#define I_DIM 11008

typedef int v4i __attribute__((ext_vector_type(4)));

// ---------------------------------------------------------------------------
// async global->LDS copy, 16B per lane (global_load_lds_dwordx4)
// ---------------------------------------------------------------------------
__device__ __forceinline__ void async_copy16(const void* g, void* l) {
  __builtin_amdgcn_global_load_lds(
      (const __attribute__((address_space(1))) void*)g,
      (__attribute__((address_space(3))) void*)l, 16, 0, 0);
}

// Stage a 128x64 int8 tile (row-major, leading dim ld) into LDS.
// LDS layout: row r occupies bytes [r*64, r*64+64), 4 chunks of 16B.
// XOR swizzle: physical chunk p holds logical (k) chunk c = p ^ ((r>>1)&3)
// so ds_read_b128 fragment reads land at 2-way bank conflicts (free).
// global_load_lds: LDS dest = wave-uniform base + lane*16, so the swizzle is
// applied to the *global* source address. 2 VMEM ops/lane.
__device__ __forceinline__ void stage_tile128(const int8_t* src, size_t ld,
                                              char* ldsbase, int wave, int lane) {
#pragma unroll
  for (int q = 0; q < 2; ++q) {
    int seg = q * 4 + wave;            // 0..7, 16 rows per segment
    int r = seg * 16 + (lane >> 2);    // tile-local row 0..127
    int p = lane & 3;                  // physical 16B chunk
    int c = p ^ ((r >> 1) & 3);        // logical k chunk
    const int8_t* g = src + (size_t)r * ld + (size_t)c * 16;
    char* lp = ldsbase + seg * 1024;
    async_copy16((const void*)g, (void*)lp);
  }
}

// Stage a 64x64 int8 tile (same layout/swizzle). 1 VMEM op/lane.
__device__ __forceinline__ void stage_tile64(const int8_t* src, size_t ld,
                                             char* ldsbase, int wave, int lane) {
  int r = wave * 16 + (lane >> 2);     // tile-local row 0..63
  int p = lane & 3;
  int c = p ^ ((r >> 1) & 3);
  const int8_t* g = src + (size_t)r * ld + (size_t)c * 16;
  char* lp = ldsbase + wave * 1024;
  async_copy16((const void*)g, (void*)lp);
}

// Load one 16x16x64 i8 MFMA A/B fragment from a swizzled LDS tile.
__device__ __forceinline__ v4i frag_load(const char* ldsbase, int rowbase, int lane) {
  int r = rowbase + (lane & 15);
  int c = (lane >> 4) ^ ((r >> 1) & 3);
  return *(const v4i*)(ldsbase + r * 64 + c * 16);
}

// ---------------------------------------------------------------------------
// int32 -> int8 pack (values already in [-127,127])
// ---------------------------------------------------------------------------
__global__ void pack_i8(const int4* __restrict__ src, char4* __restrict__ dst, int n4) {
  int stride = gridDim.x * blockDim.x;
  for (int i = blockIdx.x * blockDim.x + threadIdx.x; i < n4; i += stride) {
    int4 v = src[i];
    char4 c;
    c.x = (char)v.x; c.y = (char)v.y; c.z = (char)v.z; c.w = (char)v.w;
    dst[i] = c;
  }
}

__global__ void zero_u32(unsigned* __restrict__ p, int n) {
  int i = blockIdx.x * blockDim.x + threadIdx.x;
  if (i < n) p[i] = 0u;
}

// ---------------------------------------------------------------------------
// GEMM1 compute step: per wave 64x32 gate + 64x32 up from one K=64 tile.
// ---------------------------------------------------------------------------
__device__ __forceinline__ void g1_step(const char* LA, const char* LBG, const char* LBU,
                                        int wm, int wn, int lane,
                                        v4i (&accg)[4][2], v4i (&accu)[4][2]) {
  v4i a[4], bg[2], bu[2];
#pragma unroll
  for (int i = 0; i < 4; i++) a[i]  = frag_load(LA,  wm * 64 + i * 16, lane);
#pragma unroll
  for (int j = 0; j < 2; j++) bg[j] = frag_load(LBG, wn * 32 + j * 16, lane);
#pragma unroll
  for (int j = 0; j < 2; j++) bu[j] = frag_load(LBU, wn * 32 + j * 16, lane);
#pragma unroll
  for (int i = 0; i < 4; i++)
#pragma unroll
    for (int j = 0; j < 2; j++) {
      accg[i][j] = __builtin_amdgcn_mfma_i32_16x16x64_i8(a[i], bg[j], accg[i][j], 0, 0, 0);
      accu[i][j] = __builtin_amdgcn_mfma_i32_16x16x64_i8(a[i], bu[j], accu[i][j], 0, 0, 0);
    }
}

// ---------------------------------------------------------------------------
// GEMM1 fused: gu = x_q @ w_gate_up^T (gate col n / up col I+n share the A
// tile), epilogue y = silu(gate)*up, per-row absmax via shfl + atomicMax.
// Tile 128m x 64n (gate) + 64n (up), BK=64, 4 waves each 64x32(+64x32).
// acc = 64 regs/wave -> ~150 total -> 3 blocks/CU (occupancy was the R3
// bottleneck: MFMA 33%, HBM 15%, occ 21% = latency-bound).
// Double-buffered LDS, prefetch issued before compute, one sync per K-step.
// ---------------------------------------------------------------------------
__global__ __launch_bounds__(256, 3)
void gemm1_silu(const int8_t* __restrict__ x8,
                const int8_t* __restrict__ wgu8,
                const float* __restrict__ x_scale,
                const float* __restrict__ s_wgu,
                float* __restrict__ y,
                unsigned* __restrict__ rowmax) {
  __shared__ __align__(16) char lds0[16384];
  __shared__ __align__(16) char lds1[16384];
  char* A0 = lds0;  char* Bg0 = lds0 + 8192;  char* Bu0 = lds0 + 12288;
  char* A1 = lds1;  char* Bg1 = lds1 + 8192;  char* Bu1 = lds1 + 12288;

  const int tid = threadIdx.x;
  const int wave = tid >> 6, lane = tid & 63;
  const int wm = wave >> 1, wn = wave & 1;

  // XCD swizzle: grid = 172n x 32m = 5504 blocks, /8 = 688 per XCD.
  // m = xcd*4 + (l&3): each XCD owns 4 m-rows; the 4 m-sharers of a B panel
  // are dispatch-adjacent -> B panel read while L2-hot; A (4 x 512KB) pinned.
  const unsigned bid = blockIdx.y * gridDim.x + blockIdx.x;
  const unsigned xcd = bid & 7;
  const unsigned l   = bid >> 3;            // 0..687
  const int m0 = (int)(xcd * 4 + (l & 3)) * 128;
  const int n0 = (int)(l >> 2) * 64;        // 0..171 * 64

  v4i accg[4][2], accu[4][2];
  const v4i vzero = {0, 0, 0, 0};
#pragma unroll
  for (int i = 0; i < 4; i++)
#pragma unroll
    for (int j = 0; j < 2; j++) { accg[i][j] = vzero; accu[i][j] = vzero; }

  const int8_t* Ab  = x8 + (size_t)m0 * H_DIM;
  const int8_t* Bgb = wgu8 + (size_t)n0 * H_DIM;
  const int8_t* Bub = wgu8 + ((size_t)I_DIM + (size_t)n0) * H_DIM;

  // prologue: stage tile k=0 into buf0 (4 VMEM/lane)
  stage_tile128(Ab,  H_DIM, A0,  wave, lane);
  stage_tile64(Bgb,  H_DIM, Bg0, wave, lane);
  stage_tile64(Bub,  H_DIM, Bu0, wave, lane);
  __syncthreads();

  // H_DIM/64 = 64 K-steps, unrolled x2 (static buffer choice)
  for (int k0 = 0; k0 < H_DIM; k0 += 128) {
    {  // phase 0: prefetch k0+64 -> buf1, compute k0 from buf0
      const int kn = k0 + 64;
      if (kn < H_DIM) {
        stage_tile128(Ab + kn,  H_DIM, A1,  wave, lane);
        stage_tile64(Bgb + kn,  H_DIM, Bg1, wave, lane);
        stage_tile64(Bub + kn,  H_DIM, Bu1, wave, lane);
      }
      g1_step(A0, Bg0, Bu0, wm, wn, lane, accg, accu);
      __syncthreads();
    }
    {  // phase 1: prefetch k0+128 -> buf0, compute k0+64 from buf1
      const int kn = k0 + 128;
      if (kn < H_DIM) {
        stage_tile128(Ab + kn,  H_DIM, A0,  wave, lane);
        stage_tile64(Bgb + kn,  H_DIM, Bg0, wave, lane);
        stage_tile64(Bub + kn,  H_DIM, Bu0, wave, lane);
      }
      g1_step(A1, Bg1, Bu1, wm, wn, lane, accg, accu);
      __syncthreads();
    }
  }

  // Epilogue. C/D layout: col = lane&15, row = (lane>>4)*4 + reg.
  const int lr = lane >> 4;
  const int lc = lane & 15;
#pragma unroll
  for (int i = 0; i < 4; i++) {
#pragma unroll
    for (int t = 0; t < 4; t++) {
      const int gr = m0 + wm * 64 + i * 16 + lr * 4 + t;
      const float sx = x_scale[gr];
      float vmax = 0.f;
#pragma unroll
      for (int j = 0; j < 2; j++) {
        const int gc = n0 + wn * 32 + j * 16 + lc;
        float g = (float)accg[i][j][t] * sx * s_wgu[gc];
        float u = (float)accu[i][j][t] * sx * s_wgu[I_DIM + gc];
        float yv = (g / (1.f + expf(-g))) * u;   // silu(g) * u
        y[(size_t)gr * I_DIM + gc] = yv;
        vmax = fmaxf(vmax, fabsf(yv));
      }
      // reduce max across the 16 lanes sharing this row (lane bits 0..3)
#pragma unroll
      for (int off = 1; off < 16; off <<= 1)
        vmax = fmaxf(vmax, __shfl_xor(vmax, off, 64));
      if (lc == 0) atomicMax(&rowmax[gr], __float_as_uint(vmax));
    }
  }
}

// ---------------------------------------------------------------------------
// quantize y -> int8 with dynamic per-row scale s2 = max(|y|,1e-8)/127
// jnp.round == round-half-even == rintf
// ---------------------------------------------------------------------------
__global__ void quantize_y(const float* __restrict__ y,
                           const unsigned* __restrict__ rowmax,
                           int8_t* __restrict__ yq) {
  size_t gid = (size_t)blockIdx.x * blockDim.x + threadIdx.x;
  size_t base = gid * 4;
  if (base >= (size_t)T_DIM * I_DIM) return;
  int row = (int)(base / I_DIM);   // I_DIM % 4 == 0, packs never cross rows
  float inv = 127.f / fmaxf(__uint_as_float(rowmax[row]), 1e-8f);
  float4 v = *(const float4*)(y + base);
  char4 q;
  q.x = (char)(int)fminf(127.f, fmaxf(-128.f, rintf(v.x * inv)));
  q.y = (char)(int)fminf(127.f, fmaxf(-128.f, rintf(v.y * inv)));
  q.z = (char)(int)fminf(127.f, fmaxf(-128.f, rintf(v.z * inv)));
  q.w = (char)(int)fminf(127.f, fmaxf(-128.f, rintf(v.w * inv)));
  *(char4*)(yq + base) = q;
}

// ---------------------------------------------------------------------------
// GEMM2 compute step: per wave 64x32 from one K=64 tile.
// ---------------------------------------------------------------------------
__device__ __forceinline__ void g2_step(const char* LA, const char* LB,
                                        int wm, int wn, int lane,
                                        v4i (&acc)[4][2]) {
  v4i a[4], b[2];
#pragma unroll
  for (int i = 0; i < 4; i++) a[i] = frag_load(LA, wm * 64 + i * 16, lane);
#pragma unroll
  for (int j = 0; j < 2; j++) b[j] = frag_load(LB, wn * 32 + j * 16, lane);
#pragma unroll
  for (int i = 0; i < 4; i++)
#pragma unroll
    for (int j = 0; j < 2; j++)
      acc[i][j] = __builtin_amdgcn_mfma_i32_16x16x64_i8(a[i], b[j], acc[i][j], 0, 0, 0);
}

// ---------------------------------------------------------------------------
// GEMM2: out = (y_q @ w_down^T) * s2[row] * s_w_down[col]
// Tile 128m x 64n. acc = 32 regs/wave -> ~120 total -> 4 blocks/CU.
// ---------------------------------------------------------------------------
__global__ __launch_bounds__(256, 4)
void gemm2_scaled(const int8_t* __restrict__ yq8,
                  const int8_t* __restrict__ wd8,
                  const unsigned* __restrict__ rowmax,
                  const float* __restrict__ s_wd,
                  float* __restrict__ out) {
  __shared__ __align__(16) char lds0[12288];
  __shared__ __align__(16) char lds1[12288];
  char* A0 = lds0;  char* B0 = lds0 + 8192;
  char* A1 = lds1;  char* B1 = lds1 + 8192;

  const int tid = threadIdx.x;
  const int wave = tid >> 6, lane = tid & 63;
  const int wm = wave >> 1, wn = wave & 1;

  // XCD swizzle: grid = 64n x 32m = 2048 blocks, /8 = 256 per XCD.
  const unsigned bid = blockIdx.y * gridDim.x + blockIdx.x;
  const unsigned xcd = bid & 7;
  const unsigned l   = bid >> 3;            // 0..255
  const int m0 = (int)(xcd * 4 + (l & 3)) * 128;
  const int n0 = (int)(l >> 2) * 64;        // 0..63 * 64

  v4i acc[4][2];
  const v4i vzero = {0, 0, 0, 0};
#pragma unroll
  for (int i = 0; i < 4; i++)
#pragma unroll
    for (int j = 0; j < 2; j++) acc[i][j] = vzero;

  const int8_t* Ab = yq8 + (size_t)m0 * I_DIM;
  const int8_t* Bb = wd8 + (size_t)n0 * I_DIM;

  stage_tile128(Ab, I_DIM, A0, wave, lane);
  stage_tile64(Bb,  I_DIM, B0, wave, lane);
  __syncthreads();

  // I_DIM/64 = 172 K-steps (even), unrolled x2
  for (int k0 = 0; k0 < I_DIM; k0 += 128) {
    {
      const int kn = k0 + 64;
      if (kn < I_DIM) {
        stage_tile128(Ab + kn, I_DIM, A1, wave, lane);
        stage_tile64(Bb + kn,  I_DIM, B1, wave, lane);
      }
      g2_step(A0, B0, wm, wn, lane, acc);
      __syncthreads();
    }
    {
      const int kn = k0 + 128;
      if (kn < I_DIM) {
        stage_tile128(Ab + kn, I_DIM, A0, wave, lane);
        stage_tile64(Bb + kn,  I_DIM, B0, wave, lane);
      }
      g2_step(A1, B1, wm, wn, lane, acc);
      __syncthreads();
    }
  }

  const int lr = lane >> 4;
  const int lc = lane & 15;
#pragma unroll
  for (int i = 0; i < 4; i++) {
#pragma unroll
    for (int t = 0; t < 4; t++) {
      const int gr = m0 + wm * 64 + i * 16 + lr * 4 + t;
      const float s2 = fmaxf(__uint_as_float(rowmax[gr]), 1e-8f) / 127.f;
#pragma unroll
      for (int j = 0; j < 2; j++) {
        const int gc = n0 + wn * 32 + j * 16 + lc;
        out[(size_t)gr * H_DIM + gc] = (float)acc[i][j][t] * s2 * s_wd[gc];
      }
    }
  }
}

// ---------------------------------------------------------------------------
// launch
// ---------------------------------------------------------------------------
extern "C" void kernel_launch(void* const* d_in, const int* in_sizes, int n_in,
                              void* d_out, int out_size, void* d_ws, size_t ws_size,
                              hipStream_t stream) {
  const int*   x_q     = (const int*)d_in[0];
  const float* x_scale = (const float*)d_in[1];
  const int*   w_gu    = (const int*)d_in[2];
  const float* s_wgu   = (const float*)d_in[3];
  const int*   w_d     = (const int*)d_in[4];
  const float* s_wd    = (const float*)d_in[5];
  float* out = (float*)d_out;

  // workspace layout (bytes)
  char* ws = (char*)d_ws;
  const size_t SZ_X8   = (size_t)T_DIM * H_DIM;          //  16,777,216
  const size_t SZ_WGU8 = (size_t)2 * I_DIM * H_DIM;      //  90,177,536
  const size_t SZ_WD8  = (size_t)H_DIM * I_DIM;          //  45,088,768
  const size_t SZ_Y    = (size_t)T_DIM * I_DIM * 4;      // 180,355,072
  const size_t SZ_YQ   = (size_t)T_DIM * I_DIM;          //  45,088,768

  int8_t*   x8     = (int8_t*)ws;
  int8_t*   wgu8   = (int8_t*)(ws + SZ_X8);
  int8_t*   wd8    = (int8_t*)(ws + SZ_X8 + SZ_WGU8);
  float*    y      = (float*)(ws + SZ_X8 + SZ_WGU8 + SZ_WD8);
  int8_t*   yq8    = (int8_t*)(ws + SZ_X8 + SZ_WGU8 + SZ_WD8 + SZ_Y);
  unsigned* rowmax = (unsigned*)(ws + SZ_X8 + SZ_WGU8 + SZ_WD8 + SZ_Y + SZ_YQ);

  // 1) pack int32 -> int8
  pack_i8<<<dim3(8192), dim3(256), 0, stream>>>((const int4*)x_q,  (char4*)x8,   (int)(SZ_X8 / 4));
  pack_i8<<<dim3(8192), dim3(256), 0, stream>>>((const int4*)w_gu, (char4*)wgu8, (int)(SZ_WGU8 / 4));
  pack_i8<<<dim3(8192), dim3(256), 0, stream>>>((const int4*)w_d,  (char4*)wd8,  (int)(SZ_WD8 / 4));
  zero_u32<<<dim3(16), dim3(256), 0, stream>>>(rowmax, T_DIM);

  // 2) fused GEMM1 + silu*up + row absmax  (tile 128m x 64n, 172x32 grid)
  gemm1_silu<<<dim3(I_DIM / 64, T_DIM / 128), dim3(256), 0, stream>>>(
      x8, wgu8, x_scale, s_wgu, y, rowmax);

  // 3) dynamic per-row quantization
  quantize_y<<<dim3((unsigned)((size_t)T_DIM * I_DIM / 4 / 256)), dim3(256), 0, stream>>>(
      y, rowmax, yq8);

  // 4) GEMM2 + scale epilogue  (tile 128m x 64n, 64x32 grid)
  gemm2_scaled<<<dim3(H_DIM / 64, T_DIM / 128), dim3(256), 0, stream>>>(
      yq8, wd8, rowmax, s_wd, out);
}

// Round 5
// 1380.596 us; speedup vs baseline: 1.0340x; 1.0340x over previous
//
#include <hip/hip_runtime.h>
#include <cstdint>
#include <cstddef>

#define T_DIM 4096
#define H_DIM 4096
#define I_DIM 11008

typedef int v4i __attribute__((ext_vector_type(4)));

// ---------------------------------------------------------------------------
// async global->LDS copy, 16B per lane (global_load_lds_dwordx4)
// ---------------------------------------------------------------------------
__device__ __forceinline__ void async_copy16(const void* g, void* l) {
  __builtin_amdgcn_global_load_lds(
      (const __attribute__((address_space(1))) void*)g,
      (__attribute__((address_space(3))) void*)l, 16, 0, 0);
}

// ---------------------------------------------------------------------------
// int32 -> int8 pack (values already in [-127,127])
// ---------------------------------------------------------------------------
__global__ void pack_i8(const int4* __restrict__ src, char4* __restrict__ dst, int n4) {
  int stride = gridDim.x * blockDim.x;
  for (int i = blockIdx.x * blockDim.x + threadIdx.x; i < n4; i += stride) {
    int4 v = src[i];
    char4 c;
    c.x = (char)v.x; c.y = (char)v.y; c.z = (char)v.z; c.w = (char)v.w;
    dst[i] = c;
  }
}

__global__ void zero_u32(unsigned* __restrict__ p, int n) {
  int i = blockIdx.x * blockDim.x + threadIdx.x;
  if (i < n) p[i] = 0u;
}

// ---------------------------------------------------------------------------
// GEMM1: gu = x_q @ w_gate_up^T (gate col n / up col I+n share the A tile),
// epilogue y = silu(gate)*up, per-row absmax via shfl + atomicMax.
// 128x128 tile, BK=64, 4 waves each 64x64 gate + 64x64 up.
//
// Depth-2 pipeline (T4): 3 LDS buffers; phase t = { s_waitcnt vmcnt(6);
// s_barrier; stage tile t+2; compute tile t }. Each tile's 6 staging loads
// get ~2 compute phases of latency slack; vmcnt never drains to 0 in the
// main loop. No sched_barrier, no pointer arrays (R2's spill causes).
// All staging/frag addresses are hoisted: per-lane offsets are K-invariant
// (swizzle c = (lane>>4) ^ (((lane&15)>>1)&3) is independent of fragment
// index and wm), only the uniform K-base advances per phase.
// ---------------------------------------------------------------------------
__global__ __launch_bounds__(256, 2)
void gemm1_silu(const int8_t* __restrict__ x8,
                const int8_t* __restrict__ wgu8,
                const float* __restrict__ x_scale,
                const float* __restrict__ s_wgu,
                float* __restrict__ y,
                unsigned* __restrict__ rowmax) {
  // distinct __shared__ objects -> NoAlias: ds_reads of the compute buffer
  // can't be forced to wait on in-flight global_load_lds of another buffer
  __shared__ __align__(16) char lds0[24576];
  __shared__ __align__(16) char lds1[24576];
  __shared__ __align__(16) char lds2[24576];

  const int tid = threadIdx.x;
  const int wave = tid >> 6, lane = tid & 63;
  const int wm = wave >> 1, wn = wave & 1;

  // Supertile XCD swizzle (R3, verified): 86x32 grid = 2752 blocks, 344/XCD.
  // Each XCD: 4 m-rows x 86 n-cols, walked in 4m x 8n supertiles.
  const unsigned bid = blockIdx.y * gridDim.x + blockIdx.x;
  const unsigned xcd = bid & 7;
  const unsigned l   = bid >> 3;        // 0..343
  const unsigned s   = l >> 5;          // supertile 0..10
  const unsigned r   = l - (s << 5);    // 0..31 (0..23 in the last)
  const int m0 = (int)(xcd * 4 + (r & 3)) * 128;
  const int n0 = (int)(s * 8 + (r >> 2)) * 128;

  v4i accg[4][4], accu[4][4];
  const v4i vzero = {0, 0, 0, 0};
#pragma unroll
  for (int i = 0; i < 4; i++)
#pragma unroll
    for (int j = 0; j < 4; j++) { accg[i][j] = vzero; accu[i][j] = vzero; }

  const int8_t* Ab  = x8 + (size_t)m0 * H_DIM;
  const int8_t* Bgb = wgu8 + (size_t)n0 * H_DIM;
  const int8_t* Bub = wgu8 + ((size_t)I_DIM + (size_t)n0) * H_DIM;

  // ---- hoisted per-lane staging offsets (K-invariant) ----
  // row r_q = (q*4+wave)*16 + lane>>2, chunk c_q = (lane&3) ^ ((r_q>>1)&3)
  const int sr0 = wave * 16 + (lane >> 2);
  const int sr1 = (4 + wave) * 16 + (lane >> 2);
  const int sc0 = (lane & 3) ^ ((sr0 >> 1) & 3);
  const int sc1 = (lane & 3) ^ ((sr1 >> 1) & 3);
  const size_t vo0 = (size_t)sr0 * H_DIM + (size_t)sc0 * 16;
  const size_t vo1 = (size_t)sr1 * H_DIM + (size_t)sc1 * 16;
  const int ldsSeg0 = wave * 1024;
  const int ldsSeg1 = (4 + wave) * 1024;

  // ---- hoisted per-lane fragment offsets (K-invariant) ----
  const int cfrag = ((lane >> 4) ^ (((lane & 15) >> 1) & 3)) * 16;
  const int aoff = (wm * 64 + (lane & 15)) * 64 + cfrag;  // + i*1024
  const int boff = (wn * 64 + (lane & 15)) * 64 + cfrag;  // + j*1024

#define G1_STAGE(L, T)                                                      \
  {                                                                         \
    const int8_t* A_ = Ab + ((size_t)(T) << 6);                             \
    const int8_t* G_ = Bgb + ((size_t)(T) << 6);                            \
    const int8_t* U_ = Bub + ((size_t)(T) << 6);                            \
    async_copy16(A_ + vo0, (L) + ldsSeg0);                                  \
    async_copy16(A_ + vo1, (L) + ldsSeg1);                                  \
    async_copy16(G_ + vo0, (L) + 8192 + ldsSeg0);                           \
    async_copy16(G_ + vo1, (L) + 8192 + ldsSeg1);                           \
    async_copy16(U_ + vo0, (L) + 16384 + ldsSeg0);                          \
    async_copy16(U_ + vo1, (L) + 16384 + ldsSeg1);                          \
  }

#define G1_STEP(L)                                                          \
  {                                                                         \
    v4i a[4], bg[4], bu[4];                                                 \
    _Pragma("unroll")                                                       \
    for (int i = 0; i < 4; i++) a[i]  = *(const v4i*)((L) + aoff + i * 1024);          \
    _Pragma("unroll")                                                       \
    for (int j = 0; j < 4; j++) bg[j] = *(const v4i*)((L) + 8192 + boff + j * 1024);   \
    _Pragma("unroll")                                                       \
    for (int j = 0; j < 4; j++) bu[j] = *(const v4i*)((L) + 16384 + boff + j * 1024);  \
    _Pragma("unroll")                                                       \
    for (int i = 0; i < 4; i++)                                             \
      _Pragma("unroll")                                                     \
      for (int j = 0; j < 4; j++) {                                         \
        accg[i][j] = __builtin_amdgcn_mfma_i32_16x16x64_i8(a[i], bg[j], accg[i][j], 0, 0, 0); \
        accu[i][j] = __builtin_amdgcn_mfma_i32_16x16x64_i8(a[i], bu[j], accu[i][j], 0, 0, 0); \
      }                                                                     \
  }

  // phase t: wait tile t landed (vmcnt(6) leaves tile t+1's 6 loads in
  // flight; FIFO => oldest 6 = tile t), barrier (cross-wave completeness of
  // tile t AND everyone done computing tile t-1 => its buffer is free),
  // stage tile t+2, compute tile t.
#define G1_PHASE(Lc, Ls, T)                                                 \
  {                                                                         \
    asm volatile("s_waitcnt vmcnt(6)" ::: "memory");                        \
    __builtin_amdgcn_s_barrier();                                           \
    if ((T) + 2 < 64) G1_STAGE(Ls, (T) + 2);                                \
    G1_STEP(Lc);                                                            \
  }

  // prologue: stage tiles 0 and 1 (12 loads in flight)
  G1_STAGE(lds0, 0);
  G1_STAGE(lds1, 1);

  // 64 K-tiles: phases 0..62 in-loop (21 x 3), phase 63 peeled (63%3 == 0).
  for (int t = 0; t < 63; t += 3) {
    G1_PHASE(lds0, lds2, t)          // compute buf0, stage -> buf2
    G1_PHASE(lds1, lds0, t + 1)      // compute buf1, stage -> buf0
    G1_PHASE(lds2, lds1, t + 2)      // compute buf2, stage -> buf1
  }
  asm volatile("s_waitcnt vmcnt(0)" ::: "memory");
  __builtin_amdgcn_s_barrier();
  G1_STEP(lds0);
#undef G1_PHASE
#undef G1_STEP
#undef G1_STAGE

  // Epilogue. C/D layout (verified): col = lane&15, row = (lane>>4)*4 + reg.
  const int lr = lane >> 4;
  const int lc = lane & 15;
#pragma unroll
  for (int i = 0; i < 4; i++) {
#pragma unroll
    for (int t = 0; t < 4; t++) {
      const int gr = m0 + wm * 64 + i * 16 + lr * 4 + t;
      const float sx = x_scale[gr];
      float vmax = 0.f;
#pragma unroll
      for (int j = 0; j < 4; j++) {
        const int gc = n0 + wn * 64 + j * 16 + lc;
        float g = (float)accg[i][j][t] * sx * s_wgu[gc];
        float u = (float)accu[i][j][t] * sx * s_wgu[I_DIM + gc];
        float yv = (g / (1.f + expf(-g))) * u;   // silu(g) * u
        y[(size_t)gr * I_DIM + gc] = yv;
        vmax = fmaxf(vmax, fabsf(yv));
      }
#pragma unroll
      for (int off = 1; off < 16; off <<= 1)
        vmax = fmaxf(vmax, __shfl_xor(vmax, off, 64));
      if (lc == 0) atomicMax(&rowmax[gr], __float_as_uint(vmax));
    }
  }
}

// ---------------------------------------------------------------------------
// quantize y -> int8 with dynamic per-row scale s2 = max(|y|,1e-8)/127
// jnp.round == round-half-even == rintf
// ---------------------------------------------------------------------------
__global__ void quantize_y(const float* __restrict__ y,
                           const unsigned* __restrict__ rowmax,
                           int8_t* __restrict__ yq) {
  size_t gid = (size_t)blockIdx.x * blockDim.x + threadIdx.x;
  size_t base = gid * 4;
  if (base >= (size_t)T_DIM * I_DIM) return;
  int row = (int)(base / I_DIM);   // I_DIM % 4 == 0, packs never cross rows
  float inv = 127.f / fmaxf(__uint_as_float(rowmax[row]), 1e-8f);
  float4 v = *(const float4*)(y + base);
  char4 q;
  q.x = (char)(int)fminf(127.f, fmaxf(-128.f, rintf(v.x * inv)));
  q.y = (char)(int)fminf(127.f, fmaxf(-128.f, rintf(v.y * inv)));
  q.z = (char)(int)fminf(127.f, fmaxf(-128.f, rintf(v.z * inv)));
  q.w = (char)(int)fminf(127.f, fmaxf(-128.f, rintf(v.w * inv)));
  *(char4*)(yq + base) = q;
}

// ---------------------------------------------------------------------------
// GEMM2: out = (y_q @ w_down^T) * s2[row] * s_w_down[col]
// 128x128 tile, BK=64, same depth-2 counted-vmcnt pipeline (4 loads/stage).
// 3 x 16KB LDS, acc 64 regs -> 3 blocks/CU.
// ---------------------------------------------------------------------------
__global__ __launch_bounds__(256, 3)
void gemm2_scaled(const int8_t* __restrict__ yq8,
                  const int8_t* __restrict__ wd8,
                  const unsigned* __restrict__ rowmax,
                  const float* __restrict__ s_wd,
                  float* __restrict__ out) {
  __shared__ __align__(16) char lds0[16384];
  __shared__ __align__(16) char lds1[16384];
  __shared__ __align__(16) char lds2[16384];

  const int tid = threadIdx.x;
  const int wave = tid >> 6, lane = tid & 63;
  const int wm = wave >> 1, wn = wave & 1;

  // Supertile XCD swizzle (R3): 1024 blocks, 128/XCD = 4 supertiles of 4m x 8n.
  const unsigned bid = blockIdx.y * gridDim.x + blockIdx.x;
  const unsigned xcd = bid & 7;
  const unsigned l   = bid >> 3;        // 0..127
  const unsigned s   = l >> 5;          // 0..3
  const unsigned r   = l & 31;
  const int m0 = (int)(xcd * 4 + (r & 3)) * 128;
  const int n0 = (int)(s * 8 + (r >> 2)) * 128;

  v4i acc[4][4];
  const v4i vzero = {0, 0, 0, 0};
#pragma unroll
  for (int i = 0; i < 4; i++)
#pragma unroll
    for (int j = 0; j < 4; j++) acc[i][j] = vzero;

  const int8_t* Ab = yq8 + (size_t)m0 * I_DIM;
  const int8_t* Bb = wd8 + (size_t)n0 * I_DIM;

  const int sr0 = wave * 16 + (lane >> 2);
  const int sr1 = (4 + wave) * 16 + (lane >> 2);
  const int sc0 = (lane & 3) ^ ((sr0 >> 1) & 3);
  const int sc1 = (lane & 3) ^ ((sr1 >> 1) & 3);
  const size_t vo0 = (size_t)sr0 * I_DIM + (size_t)sc0 * 16;
  const size_t vo1 = (size_t)sr1 * I_DIM + (size_t)sc1 * 16;
  const int ldsSeg0 = wave * 1024;
  const int ldsSeg1 = (4 + wave) * 1024;

  const int cfrag = ((lane >> 4) ^ (((lane & 15) >> 1) & 3)) * 16;
  const int aoff = (wm * 64 + (lane & 15)) * 64 + cfrag;
  const int boff = (wn * 64 + (lane & 15)) * 64 + cfrag;

#define G2_STAGE(L, T)                                                      \
  {                                                                         \
    const int8_t* A_ = Ab + ((size_t)(T) << 6);                             \
    const int8_t* B_ = Bb + ((size_t)(T) << 6);                             \
    async_copy16(A_ + vo0, (L) + ldsSeg0);                                  \
    async_copy16(A_ + vo1, (L) + ldsSeg1);                                  \
    async_copy16(B_ + vo0, (L) + 8192 + ldsSeg0);                           \
    async_copy16(B_ + vo1, (L) + 8192 + ldsSeg1);                           \
  }

#define G2_STEP(L)                                                          \
  {                                                                         \
    v4i a[4], b[4];                                                         \
    _Pragma("unroll")                                                       \
    for (int i = 0; i < 4; i++) a[i] = *(const v4i*)((L) + aoff + i * 1024);        \
    _Pragma("unroll")                                                       \
    for (int j = 0; j < 4; j++) b[j] = *(const v4i*)((L) + 8192 + boff + j * 1024); \
    _Pragma("unroll")                                                       \
    for (int i = 0; i < 4; i++)                                             \
      _Pragma("unroll")                                                     \
      for (int j = 0; j < 4; j++)                                           \
        acc[i][j] = __builtin_amdgcn_mfma_i32_16x16x64_i8(a[i], b[j], acc[i][j], 0, 0, 0); \
  }

#define G2_PHASE(Lc, Ls, T)                                                 \
  {                                                                         \
    asm volatile("s_waitcnt vmcnt(4)" ::: "memory");                        \
    __builtin_amdgcn_s_barrier();                                           \
    if ((T) + 2 < 172) G2_STAGE(Ls, (T) + 2);                               \
    G2_STEP(Lc);                                                            \
  }

  G2_STAGE(lds0, 0);
  G2_STAGE(lds1, 1);

  // 172 K-tiles: phases 0..170 in-loop (57 x 3), phase 171 peeled (171%3==0).
  for (int t = 0; t < 171; t += 3) {
    G2_PHASE(lds0, lds2, t)
    G2_PHASE(lds1, lds0, t + 1)
    G2_PHASE(lds2, lds1, t + 2)
  }
  asm volatile("s_waitcnt vmcnt(0)" ::: "memory");
  __builtin_amdgcn_s_barrier();
  G2_STEP(lds0);
#undef G2_PHASE
#undef G2_STEP
#undef G2_STAGE

  const int lr = lane >> 4;
  const int lc = lane & 15;
#pragma unroll
  for (int i = 0; i < 4; i++) {
#pragma unroll
    for (int t = 0; t < 4; t++) {
      const int gr = m0 + wm * 64 + i * 16 + lr * 4 + t;
      const float s2 = fmaxf(__uint_as_float(rowmax[gr]), 1e-8f) / 127.f;
#pragma unroll
      for (int j = 0; j < 4; j++) {
        const int gc = n0 + wn * 64 + j * 16 + lc;
        out[(size_t)gr * H_DIM + gc] = (float)acc[i][j][t] * s2 * s_wd[gc];
      }
    }
  }
}

// ---------------------------------------------------------------------------
// launch
// ---------------------------------------------------------------------------
extern "C" void kernel_launch(void* const* d_in, const int* in_sizes, int n_in,
                              void* d_out, int out_size, void* d_ws, size_t ws_size,
                              hipStream_t stream) {
  const int*   x_q     = (const int*)d_in[0];
  const float* x_scale = (const float*)d_in[1];
  const int*   w_gu    = (const int*)d_in[2];
  const float* s_wgu   = (const float*)d_in[3];
  const int*   w_d     = (const int*)d_in[4];
  const float* s_wd    = (const float*)d_in[5];
  float* out = (float*)d_out;

  // workspace layout (bytes)
  char* ws = (char*)d_ws;
  const size_t SZ_X8   = (size_t)T_DIM * H_DIM;          //  16,777,216
  const size_t SZ_WGU8 = (size_t)2 * I_DIM * H_DIM;      //  90,177,536
  const size_t SZ_WD8  = (size_t)H_DIM * I_DIM;          //  45,088,768
  const size_t SZ_Y    = (size_t)T_DIM * I_DIM * 4;      // 180,355,072
  const size_t SZ_YQ   = (size_t)T_DIM * I_DIM;          //  45,088,768

  int8_t*   x8     = (int8_t*)ws;
  int8_t*   wgu8   = (int8_t*)(ws + SZ_X8);
  int8_t*   wd8    = (int8_t*)(ws + SZ_X8 + SZ_WGU8);
  float*    y      = (float*)(ws + SZ_X8 + SZ_WGU8 + SZ_WD8);
  int8_t*   yq8    = (int8_t*)(ws + SZ_X8 + SZ_WGU8 + SZ_WD8 + SZ_Y);
  unsigned* rowmax = (unsigned*)(ws + SZ_X8 + SZ_WGU8 + SZ_WD8 + SZ_Y + SZ_YQ);

  // 1) pack int32 -> int8
  pack_i8<<<dim3(8192), dim3(256), 0, stream>>>((const int4*)x_q,  (char4*)x8,   (int)(SZ_X8 / 4));
  pack_i8<<<dim3(8192), dim3(256), 0, stream>>>((const int4*)w_gu, (char4*)wgu8, (int)(SZ_WGU8 / 4));
  pack_i8<<<dim3(8192), dim3(256), 0, stream>>>((const int4*)w_d,  (char4*)wd8,  (int)(SZ_WD8 / 4));
  zero_u32<<<dim3(16), dim3(256), 0, stream>>>(rowmax, T_DIM);

  // 2) fused GEMM1 + silu*up + row absmax  (128x128 tile, 86x32 grid)
  gemm1_silu<<<dim3(I_DIM / 128, T_DIM / 128), dim3(256), 0, stream>>>(
      x8, wgu8, x_scale, s_wgu, y, rowmax);

  // 3) dynamic per-row quantization
  quantize_y<<<dim3((unsigned)((size_t)T_DIM * I_DIM / 4 / 256)), dim3(256), 0, stream>>>(
      y, rowmax, yq8);

  // 4) GEMM2 + scale epilogue  (128x128 tile, 32x32 grid)
  gemm2_scaled<<<dim3(H_DIM / 128, T_DIM / 128), dim3(256), 0, stream>>>(
      yq8, wd8, rowmax, s_wd, out);
}

// Round 6
// 1320.734 us; speedup vs baseline: 1.0809x; 1.0453x over previous
//
#include <hip/hip_runtime.h>
#include <cstdint>
#include <cstddef>

#define T_DIM 4096
#define H_DIM 4096
#define I_DIM 11008

typedef int v4i __attribute__((ext_vector_type(4)));

// ---------------------------------------------------------------------------
// async global->LDS copy, 16B per lane (global_load_lds_dwordx4)
// ---------------------------------------------------------------------------
__device__ __forceinline__ void async_copy16(const void* g, void* l) {
  __builtin_amdgcn_global_load_lds(
      (const __attribute__((address_space(1))) void*)g,
      (__attribute__((address_space(3))) void*)l, 16, 0, 0);
}

// ---------------------------------------------------------------------------
// int32 -> int8 pack (values already in [-127,127])
// ---------------------------------------------------------------------------
__global__ void pack_i8(const int4* __restrict__ src, char4* __restrict__ dst, int n4) {
  int stride = gridDim.x * blockDim.x;
  for (int i = blockIdx.x * blockDim.x + threadIdx.x; i < n4; i += stride) {
    int4 v = src[i];
    char4 c;
    c.x = (char)v.x; c.y = (char)v.y; c.z = (char)v.z; c.w = (char)v.w;
    dst[i] = c;
  }
}

__global__ void zero_u32(unsigned* __restrict__ p, int n) {
  int i = blockIdx.x * blockDim.x + threadIdx.x;
  if (i < n) p[i] = 0u;
}

// ---------------------------------------------------------------------------
// GEMM1: gu = x_q @ w_gate_up^T (gate col n / up col I+n share the A tile),
// epilogue y = silu(gate)*up, per-row absmax via shfl + atomicMax.
// 128x128 tile, BK=64, 4 waves each 64x64 gate + 64x64 up.
//
// m201-ordered phase (the R5 fix): ds_read FIRST, then stage-issue, then the
// MFMA cluster, then {vmcnt(6); s_barrier} at phase END. A gload_lds never
// precedes a ds_read in program order, so the backend waitcnt pass has no
// reason to insert a conservative vmcnt drain in front of the fragment
// reads. Cross-wave safety: each phase's ending vmcnt(6)+barrier guarantees
// tile t+1 (all waves' loads) is LDS-visible before any wave enters phase
// t+1. 3 buffers -> stage of tile t+2 issued in phase t targets the buffer
// freed at the end of phase t-1, and its loads get ~2 full phases of slack.
// vmcnt never drains to 0 in the main loop (T4).
// ---------------------------------------------------------------------------
__global__ __launch_bounds__(256, 2)
void gemm1_silu(const int8_t* __restrict__ x8,
                const int8_t* __restrict__ wgu8,
                const float* __restrict__ x_scale,
                const float* __restrict__ s_wgu,
                float* __restrict__ y,
                unsigned* __restrict__ rowmax) {
  __shared__ __align__(16) char lds0[24576];
  __shared__ __align__(16) char lds1[24576];
  __shared__ __align__(16) char lds2[24576];

  const int tid = threadIdx.x;
  const int wave = tid >> 6, lane = tid & 63;
  const int wm = wave >> 1, wn = wave & 1;

  // Supertile XCD swizzle (R3, verified): 86x32 grid = 2752 blocks, 344/XCD.
  const unsigned bid = blockIdx.y * gridDim.x + blockIdx.x;
  const unsigned xcd = bid & 7;
  const unsigned l   = bid >> 3;        // 0..343
  const unsigned s   = l >> 5;          // supertile 0..10
  const unsigned r   = l - (s << 5);    // 0..31 (0..23 in the last)
  const int m0 = (int)(xcd * 4 + (r & 3)) * 128;
  const int n0 = (int)(s * 8 + (r >> 2)) * 128;

  v4i accg[4][4], accu[4][4];
  const v4i vzero = {0, 0, 0, 0};
#pragma unroll
  for (int i = 0; i < 4; i++)
#pragma unroll
    for (int j = 0; j < 4; j++) { accg[i][j] = vzero; accu[i][j] = vzero; }

  const int8_t* Ab  = x8 + (size_t)m0 * H_DIM;
  const int8_t* Bgb = wgu8 + (size_t)n0 * H_DIM;
  const int8_t* Bub = wgu8 + ((size_t)I_DIM + (size_t)n0) * H_DIM;

  // hoisted per-lane staging offsets (K-invariant)
  const int sr0 = wave * 16 + (lane >> 2);
  const int sr1 = (4 + wave) * 16 + (lane >> 2);
  const int sc0 = (lane & 3) ^ ((sr0 >> 1) & 3);
  const int sc1 = (lane & 3) ^ ((sr1 >> 1) & 3);
  const size_t vo0 = (size_t)sr0 * H_DIM + (size_t)sc0 * 16;
  const size_t vo1 = (size_t)sr1 * H_DIM + (size_t)sc1 * 16;
  const int ldsSeg0 = wave * 1024;
  const int ldsSeg1 = (4 + wave) * 1024;

  // hoisted per-lane fragment offsets (K-invariant)
  const int cfrag = ((lane >> 4) ^ (((lane & 15) >> 1) & 3)) * 16;
  const int aoff = (wm * 64 + (lane & 15)) * 64 + cfrag;  // + i*1024
  const int boff = (wn * 64 + (lane & 15)) * 64 + cfrag;  // + j*1024

#define G1_STAGE(L, T)                                                      \
  {                                                                         \
    const int8_t* A_ = Ab + ((size_t)(T) << 6);                             \
    const int8_t* G_ = Bgb + ((size_t)(T) << 6);                            \
    const int8_t* U_ = Bub + ((size_t)(T) << 6);                            \
    async_copy16(A_ + vo0, (L) + ldsSeg0);                                  \
    async_copy16(A_ + vo1, (L) + ldsSeg1);                                  \
    async_copy16(G_ + vo0, (L) + 8192 + ldsSeg0);                           \
    async_copy16(G_ + vo1, (L) + 8192 + ldsSeg1);                           \
    async_copy16(U_ + vo0, (L) + 16384 + ldsSeg0);                          \
    async_copy16(U_ + vo1, (L) + 16384 + ldsSeg1);                          \
  }

  // phase: ds_read(tile in Lc) -> stage(T2 -> Ls) -> MFMA -> vmcnt(VM) -> bar
#define G1_PHASE(Lc, Ls, T2, DOSTAGE, VM)                                   \
  {                                                                         \
    v4i a[4], bg[4], bu[4];                                                 \
    _Pragma("unroll")                                                       \
    for (int i = 0; i < 4; i++) a[i]  = *(const v4i*)((Lc) + aoff + i * 1024);          \
    _Pragma("unroll")                                                       \
    for (int j = 0; j < 4; j++) bg[j] = *(const v4i*)((Lc) + 8192 + boff + j * 1024);   \
    _Pragma("unroll")                                                       \
    for (int j = 0; j < 4; j++) bu[j] = *(const v4i*)((Lc) + 16384 + boff + j * 1024);  \
    if (DOSTAGE) G1_STAGE(Ls, T2);                                          \
    __builtin_amdgcn_s_setprio(1);                                          \
    _Pragma("unroll")                                                       \
    for (int i = 0; i < 4; i++)                                             \
      _Pragma("unroll")                                                     \
      for (int j = 0; j < 4; j++) {                                         \
        accg[i][j] = __builtin_amdgcn_mfma_i32_16x16x64_i8(a[i], bg[j], accg[i][j], 0, 0, 0); \
        accu[i][j] = __builtin_amdgcn_mfma_i32_16x16x64_i8(a[i], bu[j], accu[i][j], 0, 0, 0); \
      }                                                                     \
    __builtin_amdgcn_s_setprio(0);                                          \
    asm volatile("s_waitcnt " VM ::: "memory");                             \
    __builtin_amdgcn_s_barrier();                                           \
  }

  // prologue: stage tiles 0,1 (12 loads in flight); wait tile 0; barrier
  G1_STAGE(lds0, 0);
  G1_STAGE(lds1, 1);
  asm volatile("s_waitcnt vmcnt(6)" ::: "memory");
  __builtin_amdgcn_s_barrier();

  // 64 K-tiles: phases 0..59 in-loop (20 x 3), 60..63 peeled with static VM.
  for (int t = 0; t < 60; t += 3) {
    G1_PHASE(lds0, lds2, t + 2, 1, "vmcnt(6)")
    G1_PHASE(lds1, lds0, t + 3, 1, "vmcnt(6)")
    G1_PHASE(lds2, lds1, t + 4, 1, "vmcnt(6)")
  }
  G1_PHASE(lds0, lds2, 62, 1, "vmcnt(6)")   // t=60
  G1_PHASE(lds1, lds0, 63, 1, "vmcnt(6)")   // t=61
  G1_PHASE(lds2, lds0,  0, 0, "vmcnt(0)")   // t=62: no stage, drain tile 63
  G1_PHASE(lds0, lds0,  0, 0, "vmcnt(0)")   // t=63: final (waits are free)
#undef G1_PHASE
#undef G1_STAGE

  // Epilogue. C/D layout (verified): col = lane&15, row = (lane>>4)*4 + reg.
  const int lr = lane >> 4;
  const int lc = lane & 15;
#pragma unroll
  for (int i = 0; i < 4; i++) {
#pragma unroll
    for (int t = 0; t < 4; t++) {
      const int gr = m0 + wm * 64 + i * 16 + lr * 4 + t;
      const float sx = x_scale[gr];
      float vmax = 0.f;
#pragma unroll
      for (int j = 0; j < 4; j++) {
        const int gc = n0 + wn * 64 + j * 16 + lc;
        float g = (float)accg[i][j][t] * sx * s_wgu[gc];
        float u = (float)accu[i][j][t] * sx * s_wgu[I_DIM + gc];
        float yv = (g / (1.f + expf(-g))) * u;   // silu(g) * u
        y[(size_t)gr * I_DIM + gc] = yv;
        vmax = fmaxf(vmax, fabsf(yv));
      }
#pragma unroll
      for (int off = 1; off < 16; off <<= 1)
        vmax = fmaxf(vmax, __shfl_xor(vmax, off, 64));
      if (lc == 0) atomicMax(&rowmax[gr], __float_as_uint(vmax));
    }
  }
}

// ---------------------------------------------------------------------------
// quantize y -> int8 with dynamic per-row scale s2 = max(|y|,1e-8)/127
// jnp.round == round-half-even == rintf
// ---------------------------------------------------------------------------
__global__ void quantize_y(const float* __restrict__ y,
                           const unsigned* __restrict__ rowmax,
                           int8_t* __restrict__ yq) {
  size_t gid = (size_t)blockIdx.x * blockDim.x + threadIdx.x;
  size_t base = gid * 4;
  if (base >= (size_t)T_DIM * I_DIM) return;
  int row = (int)(base / I_DIM);   // I_DIM % 4 == 0, packs never cross rows
  float inv = 127.f / fmaxf(__uint_as_float(rowmax[row]), 1e-8f);
  float4 v = *(const float4*)(y + base);
  char4 q;
  q.x = (char)(int)fminf(127.f, fmaxf(-128.f, rintf(v.x * inv)));
  q.y = (char)(int)fminf(127.f, fmaxf(-128.f, rintf(v.y * inv)));
  q.z = (char)(int)fminf(127.f, fmaxf(-128.f, rintf(v.z * inv)));
  q.w = (char)(int)fminf(127.f, fmaxf(-128.f, rintf(v.w * inv)));
  *(char4*)(yq + base) = q;
}

// ---------------------------------------------------------------------------
// GEMM2: out = (y_q @ w_down^T) * s2[row] * s_w_down[col]
// 128x128 tile, BK=64, same m201-ordered phase (4 loads/stage, vmcnt(4)).
// ---------------------------------------------------------------------------
__global__ __launch_bounds__(256, 3)
void gemm2_scaled(const int8_t* __restrict__ yq8,
                  const int8_t* __restrict__ wd8,
                  const unsigned* __restrict__ rowmax,
                  const float* __restrict__ s_wd,
                  float* __restrict__ out) {
  __shared__ __align__(16) char lds0[16384];
  __shared__ __align__(16) char lds1[16384];
  __shared__ __align__(16) char lds2[16384];

  const int tid = threadIdx.x;
  const int wave = tid >> 6, lane = tid & 63;
  const int wm = wave >> 1, wn = wave & 1;

  // Supertile XCD swizzle (R3): 1024 blocks, 128/XCD = 4 supertiles of 4m x 8n.
  const unsigned bid = blockIdx.y * gridDim.x + blockIdx.x;
  const unsigned xcd = bid & 7;
  const unsigned l   = bid >> 3;        // 0..127
  const unsigned s   = l >> 5;          // 0..3
  const unsigned r   = l & 31;
  const int m0 = (int)(xcd * 4 + (r & 3)) * 128;
  const int n0 = (int)(s * 8 + (r >> 2)) * 128;

  v4i acc[4][4];
  const v4i vzero = {0, 0, 0, 0};
#pragma unroll
  for (int i = 0; i < 4; i++)
#pragma unroll
    for (int j = 0; j < 4; j++) acc[i][j] = vzero;

  const int8_t* Ab = yq8 + (size_t)m0 * I_DIM;
  const int8_t* Bb = wd8 + (size_t)n0 * I_DIM;

  const int sr0 = wave * 16 + (lane >> 2);
  const int sr1 = (4 + wave) * 16 + (lane >> 2);
  const int sc0 = (lane & 3) ^ ((sr0 >> 1) & 3);
  const int sc1 = (lane & 3) ^ ((sr1 >> 1) & 3);
  const size_t vo0 = (size_t)sr0 * I_DIM + (size_t)sc0 * 16;
  const size_t vo1 = (size_t)sr1 * I_DIM + (size_t)sc1 * 16;
  const int ldsSeg0 = wave * 1024;
  const int ldsSeg1 = (4 + wave) * 1024;

  const int cfrag = ((lane >> 4) ^ (((lane & 15) >> 1) & 3)) * 16;
  const int aoff = (wm * 64 + (lane & 15)) * 64 + cfrag;
  const int boff = (wn * 64 + (lane & 15)) * 64 + cfrag;

#define G2_STAGE(L, T)                                                      \
  {                                                                         \
    const int8_t* A_ = Ab + ((size_t)(T) << 6);                             \
    const int8_t* B_ = Bb + ((size_t)(T) << 6);                             \
    async_copy16(A_ + vo0, (L) + ldsSeg0);                                  \
    async_copy16(A_ + vo1, (L) + ldsSeg1);                                  \
    async_copy16(B_ + vo0, (L) + 8192 + ldsSeg0);                           \
    async_copy16(B_ + vo1, (L) + 8192 + ldsSeg1);                           \
  }

#define G2_PHASE(Lc, Ls, T2, DOSTAGE, VM)                                   \
  {                                                                         \
    v4i a[4], b[4];                                                         \
    _Pragma("unroll")                                                       \
    for (int i = 0; i < 4; i++) a[i] = *(const v4i*)((Lc) + aoff + i * 1024);        \
    _Pragma("unroll")                                                       \
    for (int j = 0; j < 4; j++) b[j] = *(const v4i*)((Lc) + 8192 + boff + j * 1024); \
    if (DOSTAGE) G2_STAGE(Ls, T2);                                          \
    __builtin_amdgcn_s_setprio(1);                                          \
    _Pragma("unroll")                                                       \
    for (int i = 0; i < 4; i++)                                             \
      _Pragma("unroll")                                                     \
      for (int j = 0; j < 4; j++)                                           \
        acc[i][j] = __builtin_amdgcn_mfma_i32_16x16x64_i8(a[i], b[j], acc[i][j], 0, 0, 0); \
    __builtin_amdgcn_s_setprio(0);                                          \
    asm volatile("s_waitcnt " VM ::: "memory");                             \
    __builtin_amdgcn_s_barrier();                                           \
  }

  G2_STAGE(lds0, 0);
  G2_STAGE(lds1, 1);
  asm volatile("s_waitcnt vmcnt(4)" ::: "memory");
  __builtin_amdgcn_s_barrier();

  // 172 K-tiles: phases 0..167 in-loop (56 x 3), 168..171 peeled.
  for (int t = 0; t < 168; t += 3) {
    G2_PHASE(lds0, lds2, t + 2, 1, "vmcnt(4)")
    G2_PHASE(lds1, lds0, t + 3, 1, "vmcnt(4)")
    G2_PHASE(lds2, lds1, t + 4, 1, "vmcnt(4)")
  }
  G2_PHASE(lds0, lds2, 170, 1, "vmcnt(4)")  // t=168
  G2_PHASE(lds1, lds0, 171, 1, "vmcnt(4)")  // t=169
  G2_PHASE(lds2, lds0,   0, 0, "vmcnt(0)")  // t=170: drain tile 171
  G2_PHASE(lds0, lds0,   0, 0, "vmcnt(0)")  // t=171: final
#undef G2_PHASE
#undef G2_STAGE

  const int lr = lane >> 4;
  const int lc = lane & 15;
#pragma unroll
  for (int i = 0; i < 4; i++) {
#pragma unroll
    for (int t = 0; t < 4; t++) {
      const int gr = m0 + wm * 64 + i * 16 + lr * 4 + t;
      const float s2 = fmaxf(__uint_as_float(rowmax[gr]), 1e-8f) / 127.f;
#pragma unroll
      for (int j = 0; j < 4; j++) {
        const int gc = n0 + wn * 64 + j * 16 + lc;
        out[(size_t)gr * H_DIM + gc] = (float)acc[i][j][t] * s2 * s_wd[gc];
      }
    }
  }
}

// ---------------------------------------------------------------------------
// launch
// ---------------------------------------------------------------------------
extern "C" void kernel_launch(void* const* d_in, const int* in_sizes, int n_in,
                              void* d_out, int out_size, void* d_ws, size_t ws_size,
                              hipStream_t stream) {
  const int*   x_q     = (const int*)d_in[0];
  const float* x_scale = (const float*)d_in[1];
  const int*   w_gu    = (const int*)d_in[2];
  const float* s_wgu   = (const float*)d_in[3];
  const int*   w_d     = (const int*)d_in[4];
  const float* s_wd    = (const float*)d_in[5];
  float* out = (float*)d_out;

  // workspace layout (bytes)
  char* ws = (char*)d_ws;
  const size_t SZ_X8   = (size_t)T_DIM * H_DIM;          //  16,777,216
  const size_t SZ_WGU8 = (size_t)2 * I_DIM * H_DIM;      //  90,177,536
  const size_t SZ_WD8  = (size_t)H_DIM * I_DIM;          //  45,088,768
  const size_t SZ_Y    = (size_t)T_DIM * I_DIM * 4;      // 180,355,072
  const size_t SZ_YQ   = (size_t)T_DIM * I_DIM;          //  45,088,768

  int8_t*   x8     = (int8_t*)ws;
  int8_t*   wgu8   = (int8_t*)(ws + SZ_X8);
  int8_t*   wd8    = (int8_t*)(ws + SZ_X8 + SZ_WGU8);
  float*    y      = (float*)(ws + SZ_X8 + SZ_WGU8 + SZ_WD8);
  int8_t*   yq8    = (int8_t*)(ws + SZ_X8 + SZ_WGU8 + SZ_WD8 + SZ_Y);
  unsigned* rowmax = (unsigned*)(ws + SZ_X8 + SZ_WGU8 + SZ_WD8 + SZ_Y + SZ_YQ);

  // 1) pack int32 -> int8
  pack_i8<<<dim3(8192), dim3(256), 0, stream>>>((const int4*)x_q,  (char4*)x8,   (int)(SZ_X8 / 4));
  pack_i8<<<dim3(8192), dim3(256), 0, stream>>>((const int4*)w_gu, (char4*)wgu8, (int)(SZ_WGU8 / 4));
  pack_i8<<<dim3(8192), dim3(256), 0, stream>>>((const int4*)w_d,  (char4*)wd8,  (int)(SZ_WD8 / 4));
  zero_u32<<<dim3(16), dim3(256), 0, stream>>>(rowmax, T_DIM);

  // 2) fused GEMM1 + silu*up + row absmax  (128x128 tile, 86x32 grid)
  gemm1_silu<<<dim3(I_DIM / 128, T_DIM / 128), dim3(256), 0, stream>>>(
      x8, wgu8, x_scale, s_wgu, y, rowmax);

  // 3) dynamic per-row quantization
  quantize_y<<<dim3((unsigned)((size_t)T_DIM * I_DIM / 4 / 256)), dim3(256), 0, stream>>>(
      y, rowmax, yq8);

  // 4) GEMM2 + scale epilogue  (128x128 tile, 32x32 grid)
  gemm2_scaled<<<dim3(H_DIM / 128, T_DIM / 128), dim3(256), 0, stream>>>(
      yq8, wd8, rowmax, s_wd, out);
}

// Round 7
// 1287.552 us; speedup vs baseline: 1.1087x; 1.0258x over previous
//
#include <hip/hip_runtime.h>
#include <cstdint>
#include <cstddef>

#define T_DIM 4096
#define H_DIM 4096
#define I_DIM 11008

typedef int v4i __attribute__((ext_vector_type(4)));

// ---------------------------------------------------------------------------
// async global->LDS copy, 16B per lane (global_load_lds_dwordx4)
// ---------------------------------------------------------------------------
__device__ __forceinline__ void async_copy16(const void* g, void* l) {
  __builtin_amdgcn_global_load_lds(
      (const __attribute__((address_space(1))) void*)g,
      (__attribute__((address_space(3))) void*)l, 16, 0, 0);
}

// ---------------------------------------------------------------------------
// int32 -> int8 pack (values already in [-127,127])
// ---------------------------------------------------------------------------
__global__ void pack_i8(const int4* __restrict__ src, char4* __restrict__ dst, int n4) {
  int stride = gridDim.x * blockDim.x;
  for (int i = blockIdx.x * blockDim.x + threadIdx.x; i < n4; i += stride) {
    int4 v = src[i];
    char4 c;
    c.x = (char)v.x; c.y = (char)v.y; c.z = (char)v.z; c.w = (char)v.w;
    dst[i] = c;
  }
}

__global__ void zero_u32(unsigned* __restrict__ p, int n) {
  int i = blockIdx.x * blockDim.x + threadIdx.x;
  if (i < n) p[i] = 0u;
}

// ---------------------------------------------------------------------------
// GEMM1: gu = x_q @ w_gate_up^T (gate col n / up col I+n share the A tile),
// epilogue y = silu(gate)*up, per-row absmax via shfl + atomicMax.
// 128x128 tile, BK=64, 4 waves each 64x64 gate + 64x64 up.
// m201-ordered phase: ds_read FIRST, then stage-issue, then MFMA cluster,
// then {vmcnt(6); s_barrier} at phase END (R6-verified: +3.3 MfmaUtil, no
// spills). 3 buffers, depth-2 slack, vmcnt never 0 in-loop (T4).
// ---------------------------------------------------------------------------
__global__ __launch_bounds__(256, 2)
void gemm1_silu(const int8_t* __restrict__ x8,
                const int8_t* __restrict__ wgu8,
                const float* __restrict__ x_scale,
                const float* __restrict__ s_wgu,
                float* __restrict__ y,
                unsigned* __restrict__ rowmax) {
  __shared__ __align__(16) char lds0[24576];
  __shared__ __align__(16) char lds1[24576];
  __shared__ __align__(16) char lds2[24576];

  const int tid = threadIdx.x;
  const int wave = tid >> 6, lane = tid & 63;
  const int wm = wave >> 1, wn = wave & 1;

  // Supertile XCD swizzle (R3, verified): 86x32 grid = 2752 blocks, 344/XCD.
  const unsigned bid = blockIdx.y * gridDim.x + blockIdx.x;
  const unsigned xcd = bid & 7;
  const unsigned l   = bid >> 3;        // 0..343
  const unsigned s   = l >> 5;          // supertile 0..10
  const unsigned r   = l - (s << 5);    // 0..31 (0..23 in the last)
  const int m0 = (int)(xcd * 4 + (r & 3)) * 128;
  const int n0 = (int)(s * 8 + (r >> 2)) * 128;

  v4i accg[4][4], accu[4][4];
  const v4i vzero = {0, 0, 0, 0};
#pragma unroll
  for (int i = 0; i < 4; i++)
#pragma unroll
    for (int j = 0; j < 4; j++) { accg[i][j] = vzero; accu[i][j] = vzero; }

  const int8_t* Ab  = x8 + (size_t)m0 * H_DIM;
  const int8_t* Bgb = wgu8 + (size_t)n0 * H_DIM;
  const int8_t* Bub = wgu8 + ((size_t)I_DIM + (size_t)n0) * H_DIM;

  // hoisted per-lane staging offsets (K-invariant)
  const int sr0 = wave * 16 + (lane >> 2);
  const int sr1 = (4 + wave) * 16 + (lane >> 2);
  const int sc0 = (lane & 3) ^ ((sr0 >> 1) & 3);
  const int sc1 = (lane & 3) ^ ((sr1 >> 1) & 3);
  const size_t vo0 = (size_t)sr0 * H_DIM + (size_t)sc0 * 16;
  const size_t vo1 = (size_t)sr1 * H_DIM + (size_t)sc1 * 16;
  const int ldsSeg0 = wave * 1024;
  const int ldsSeg1 = (4 + wave) * 1024;

  // hoisted per-lane fragment offsets (K-invariant)
  const int cfrag = ((lane >> 4) ^ (((lane & 15) >> 1) & 3)) * 16;
  const int aoff = (wm * 64 + (lane & 15)) * 64 + cfrag;  // + i*1024
  const int boff = (wn * 64 + (lane & 15)) * 64 + cfrag;  // + j*1024

#define G1_STAGE(L, T)                                                      \
  {                                                                         \
    const int8_t* A_ = Ab + ((size_t)(T) << 6);                             \
    const int8_t* G_ = Bgb + ((size_t)(T) << 6);                            \
    const int8_t* U_ = Bub + ((size_t)(T) << 6);                            \
    async_copy16(A_ + vo0, (L) + ldsSeg0);                                  \
    async_copy16(A_ + vo1, (L) + ldsSeg1);                                  \
    async_copy16(G_ + vo0, (L) + 8192 + ldsSeg0);                           \
    async_copy16(G_ + vo1, (L) + 8192 + ldsSeg1);                           \
    async_copy16(U_ + vo0, (L) + 16384 + ldsSeg0);                          \
    async_copy16(U_ + vo1, (L) + 16384 + ldsSeg1);                          \
  }

#define G1_PHASE(Lc, Ls, T2, DOSTAGE, VM)                                   \
  {                                                                         \
    v4i a[4], bg[4], bu[4];                                                 \
    _Pragma("unroll")                                                       \
    for (int i = 0; i < 4; i++) a[i]  = *(const v4i*)((Lc) + aoff + i * 1024);          \
    _Pragma("unroll")                                                       \
    for (int j = 0; j < 4; j++) bg[j] = *(const v4i*)((Lc) + 8192 + boff + j * 1024);   \
    _Pragma("unroll")                                                       \
    for (int j = 0; j < 4; j++) bu[j] = *(const v4i*)((Lc) + 16384 + boff + j * 1024);  \
    if (DOSTAGE) G1_STAGE(Ls, T2);                                          \
    __builtin_amdgcn_s_setprio(1);                                          \
    _Pragma("unroll")                                                       \
    for (int i = 0; i < 4; i++)                                             \
      _Pragma("unroll")                                                     \
      for (int j = 0; j < 4; j++) {                                         \
        accg[i][j] = __builtin_amdgcn_mfma_i32_16x16x64_i8(a[i], bg[j], accg[i][j], 0, 0, 0); \
        accu[i][j] = __builtin_amdgcn_mfma_i32_16x16x64_i8(a[i], bu[j], accu[i][j], 0, 0, 0); \
      }                                                                     \
    __builtin_amdgcn_s_setprio(0);                                          \
    asm volatile("s_waitcnt " VM ::: "memory");                             \
    __builtin_amdgcn_s_barrier();                                           \
  }

  G1_STAGE(lds0, 0);
  G1_STAGE(lds1, 1);
  asm volatile("s_waitcnt vmcnt(6)" ::: "memory");
  __builtin_amdgcn_s_barrier();

  // 64 K-tiles: phases 0..59 in-loop (20 x 3), 60..63 peeled with static VM.
  for (int t = 0; t < 60; t += 3) {
    G1_PHASE(lds0, lds2, t + 2, 1, "vmcnt(6)")
    G1_PHASE(lds1, lds0, t + 3, 1, "vmcnt(6)")
    G1_PHASE(lds2, lds1, t + 4, 1, "vmcnt(6)")
  }
  G1_PHASE(lds0, lds2, 62, 1, "vmcnt(6)")   // t=60
  G1_PHASE(lds1, lds0, 63, 1, "vmcnt(6)")   // t=61
  G1_PHASE(lds2, lds0,  0, 0, "vmcnt(0)")   // t=62: no stage, drain tile 63
  G1_PHASE(lds0, lds0,  0, 0, "vmcnt(0)")   // t=63: final
#undef G1_PHASE
#undef G1_STAGE

  // Epilogue. C/D layout (verified): col = lane&15, row = (lane>>4)*4 + reg.
  const int lr = lane >> 4;
  const int lc = lane & 15;
#pragma unroll
  for (int i = 0; i < 4; i++) {
#pragma unroll
    for (int t = 0; t < 4; t++) {
      const int gr = m0 + wm * 64 + i * 16 + lr * 4 + t;
      const float sx = x_scale[gr];
      float vmax = 0.f;
#pragma unroll
      for (int j = 0; j < 4; j++) {
        const int gc = n0 + wn * 64 + j * 16 + lc;
        float g = (float)accg[i][j][t] * sx * s_wgu[gc];
        float u = (float)accu[i][j][t] * sx * s_wgu[I_DIM + gc];
        float yv = (g / (1.f + expf(-g))) * u;   // silu(g) * u
        y[(size_t)gr * I_DIM + gc] = yv;
        vmax = fmaxf(vmax, fabsf(yv));
      }
#pragma unroll
      for (int off = 1; off < 16; off <<= 1)
        vmax = fmaxf(vmax, __shfl_xor(vmax, off, 64));
      if (lc == 0) atomicMax(&rowmax[gr], __float_as_uint(vmax));
    }
  }
}

// ---------------------------------------------------------------------------
// quantize y -> int8 with dynamic per-row scale s2 = max(|y|,1e-8)/127
// jnp.round == round-half-even == rintf
// ---------------------------------------------------------------------------
__global__ void quantize_y(const float* __restrict__ y,
                           const unsigned* __restrict__ rowmax,
                           int8_t* __restrict__ yq) {
  size_t gid = (size_t)blockIdx.x * blockDim.x + threadIdx.x;
  size_t base = gid * 4;
  if (base >= (size_t)T_DIM * I_DIM) return;
  int row = (int)(base / I_DIM);   // I_DIM % 4 == 0, packs never cross rows
  float inv = 127.f / fmaxf(__uint_as_float(rowmax[row]), 1e-8f);
  float4 v = *(const float4*)(y + base);
  char4 q;
  q.x = (char)(int)fminf(127.f, fmaxf(-128.f, rintf(v.x * inv)));
  q.y = (char)(int)fminf(127.f, fmaxf(-128.f, rintf(v.y * inv)));
  q.z = (char)(int)fminf(127.f, fmaxf(-128.f, rintf(v.z * inv)));
  q.w = (char)(int)fminf(127.f, fmaxf(-128.f, rintf(v.w * inv)));
  *(char4*)(yq + base) = q;
}

// ---------------------------------------------------------------------------
// GEMM2: out = (y_q @ w_down^T) * s2[row] * s_w_down[col]
// R7 restructure: 128m x 256n tile (was 128x128). Per wave 64m x 128n ->
// 4x8 frags, 32 MFMA/phase (same per-phase budget as gemm1's proven shape;
// the old 16-MFMA phase amortized the same overhead over half the work).
// Grid 512 blocks = exactly 2/CU, one generation of 172 phases.
// Staging: 2 A + 4 B loads/lane = 24KB/tile; same counted-vmcnt(6) pipeline.
// ---------------------------------------------------------------------------
__global__ __launch_bounds__(256, 2)
void gemm2_scaled(const int8_t* __restrict__ yq8,
                  const int8_t* __restrict__ wd8,
                  const unsigned* __restrict__ rowmax,
                  const float* __restrict__ s_wd,
                  float* __restrict__ out) {
  __shared__ __align__(16) char lds0[24576];
  __shared__ __align__(16) char lds1[24576];
  __shared__ __align__(16) char lds2[24576];

  const int tid = threadIdx.x;
  const int wave = tid >> 6, lane = tid & 63;
  const int wm = wave >> 1, wn = wave & 1;

  // XCD swizzle: grid = 16n x 32m = 512 blocks, 64/XCD. m = xcd*4 + (l&3):
  // the 4 m-sharers of each B panel are dispatch-adjacent -> L2-hot.
  const unsigned bid = blockIdx.y * gridDim.x + blockIdx.x;
  const unsigned xcd = bid & 7;
  const unsigned l   = bid >> 3;            // 0..63
  const int m0 = (int)(xcd * 4 + (l & 3)) * 128;
  const int n0 = (int)(l >> 2) * 256;       // 0..15 * 256

  v4i acc[4][8];
  const v4i vzero = {0, 0, 0, 0};
#pragma unroll
  for (int i = 0; i < 4; i++)
#pragma unroll
    for (int j = 0; j < 8; j++) acc[i][j] = vzero;

  const int8_t* Ab = yq8 + (size_t)m0 * I_DIM;
  const int8_t* Bb = wd8 + (size_t)n0 * I_DIM;

  // staging offsets: A tile 128 rows (2 loads/lane, segs wave, wave+4),
  // B tile 256 rows (4 loads/lane, segs wave, wave+4, wave+8, wave+12).
  const int lrow = lane >> 2;
  const int lchk = lane & 3;
  int srA[2], srB[4];
  srA[0] = wave * 16 + lrow;        srA[1] = (4 + wave) * 16 + lrow;
#pragma unroll
  for (int q = 0; q < 4; q++) srB[q] = (q * 4 + wave) * 16 + lrow;
  size_t voA[2], voB[4];
#pragma unroll
  for (int q = 0; q < 2; q++)
    voA[q] = (size_t)srA[q] * I_DIM + (size_t)(lchk ^ ((srA[q] >> 1) & 3)) * 16;
#pragma unroll
  for (int q = 0; q < 4; q++)
    voB[q] = (size_t)srB[q] * I_DIM + (size_t)(lchk ^ ((srB[q] >> 1) & 3)) * 16;
  const int segA0 = wave * 1024, segA1 = (4 + wave) * 1024;

  const int cfrag = ((lane >> 4) ^ (((lane & 15) >> 1) & 3)) * 16;
  const int aoff = (wm * 64 + (lane & 15)) * 64 + cfrag;    // + i*1024, i<4
  const int boff = (wn * 128 + (lane & 15)) * 64 + cfrag;   // + j*1024, j<8

#define G2_STAGE(L, T)                                                      \
  {                                                                         \
    const int8_t* A_ = Ab + ((size_t)(T) << 6);                             \
    const int8_t* B_ = Bb + ((size_t)(T) << 6);                             \
    async_copy16(A_ + voA[0], (L) + segA0);                                 \
    async_copy16(A_ + voA[1], (L) + segA1);                                 \
    async_copy16(B_ + voB[0], (L) + 8192 + segA0);                          \
    async_copy16(B_ + voB[1], (L) + 8192 + segA1);                          \
    async_copy16(B_ + voB[2], (L) + 8192 + segA0 + 8192);                   \
    async_copy16(B_ + voB[3], (L) + 8192 + segA1 + 8192);                   \
  }

#define G2_PHASE(Lc, Ls, T2, DOSTAGE, VM)                                   \
  {                                                                         \
    v4i a[4], b[8];                                                         \
    _Pragma("unroll")                                                       \
    for (int i = 0; i < 4; i++) a[i] = *(const v4i*)((Lc) + aoff + i * 1024);        \
    _Pragma("unroll")                                                       \
    for (int j = 0; j < 8; j++) b[j] = *(const v4i*)((Lc) + 8192 + boff + j * 1024); \
    if (DOSTAGE) G2_STAGE(Ls, T2);                                          \
    __builtin_amdgcn_s_setprio(1);                                          \
    _Pragma("unroll")                                                       \
    for (int i = 0; i < 4; i++)                                             \
      _Pragma("unroll")                                                     \
      for (int j = 0; j < 8; j++)                                           \
        acc[i][j] = __builtin_amdgcn_mfma_i32_16x16x64_i8(a[i], b[j], acc[i][j], 0, 0, 0); \
    __builtin_amdgcn_s_setprio(0);                                          \
    asm volatile("s_waitcnt " VM ::: "memory");                             \
    __builtin_amdgcn_s_barrier();                                           \
  }

  G2_STAGE(lds0, 0);
  G2_STAGE(lds1, 1);
  asm volatile("s_waitcnt vmcnt(6)" ::: "memory");
  __builtin_amdgcn_s_barrier();

  // 172 K-tiles: phases 0..167 in-loop (56 x 3), 168..171 peeled.
  for (int t = 0; t < 168; t += 3) {
    G2_PHASE(lds0, lds2, t + 2, 1, "vmcnt(6)")
    G2_PHASE(lds1, lds0, t + 3, 1, "vmcnt(6)")
    G2_PHASE(lds2, lds1, t + 4, 1, "vmcnt(6)")
  }
  G2_PHASE(lds0, lds2, 170, 1, "vmcnt(6)")  // t=168
  G2_PHASE(lds1, lds0, 171, 1, "vmcnt(6)")  // t=169
  G2_PHASE(lds2, lds0,   0, 0, "vmcnt(0)")  // t=170: drain tile 171
  G2_PHASE(lds0, lds0,   0, 0, "vmcnt(0)")  // t=171: final
#undef G2_PHASE
#undef G2_STAGE

  const int lr = lane >> 4;
  const int lc = lane & 15;
#pragma unroll
  for (int i = 0; i < 4; i++) {
#pragma unroll
    for (int t = 0; t < 4; t++) {
      const int gr = m0 + wm * 64 + i * 16 + lr * 4 + t;
      const float s2 = fmaxf(__uint_as_float(rowmax[gr]), 1e-8f) / 127.f;
#pragma unroll
      for (int j = 0; j < 8; j++) {
        const int gc = n0 + wn * 128 + j * 16 + lc;
        out[(size_t)gr * H_DIM + gc] = (float)acc[i][j][t] * s2 * s_wd[gc];
      }
    }
  }
}

// ---------------------------------------------------------------------------
// launch
// ---------------------------------------------------------------------------
extern "C" void kernel_launch(void* const* d_in, const int* in_sizes, int n_in,
                              void* d_out, int out_size, void* d_ws, size_t ws_size,
                              hipStream_t stream) {
  const int*   x_q     = (const int*)d_in[0];
  const float* x_scale = (const float*)d_in[1];
  const int*   w_gu    = (const int*)d_in[2];
  const float* s_wgu   = (const float*)d_in[3];
  const int*   w_d     = (const int*)d_in[4];
  const float* s_wd    = (const float*)d_in[5];
  float* out = (float*)d_out;

  // workspace layout (bytes)
  char* ws = (char*)d_ws;
  const size_t SZ_X8   = (size_t)T_DIM * H_DIM;          //  16,777,216
  const size_t SZ_WGU8 = (size_t)2 * I_DIM * H_DIM;      //  90,177,536
  const size_t SZ_WD8  = (size_t)H_DIM * I_DIM;          //  45,088,768
  const size_t SZ_Y    = (size_t)T_DIM * I_DIM * 4;      // 180,355,072
  const size_t SZ_YQ   = (size_t)T_DIM * I_DIM;          //  45,088,768

  int8_t*   x8     = (int8_t*)ws;
  int8_t*   wgu8   = (int8_t*)(ws + SZ_X8);
  int8_t*   wd8    = (int8_t*)(ws + SZ_X8 + SZ_WGU8);
  float*    y      = (float*)(ws + SZ_X8 + SZ_WGU8 + SZ_WD8);
  int8_t*   yq8    = (int8_t*)(ws + SZ_X8 + SZ_WGU8 + SZ_WD8 + SZ_Y);
  unsigned* rowmax = (unsigned*)(ws + SZ_X8 + SZ_WGU8 + SZ_WD8 + SZ_Y + SZ_YQ);

  // 1) pack int32 -> int8
  pack_i8<<<dim3(8192), dim3(256), 0, stream>>>((const int4*)x_q,  (char4*)x8,   (int)(SZ_X8 / 4));
  pack_i8<<<dim3(8192), dim3(256), 0, stream>>>((const int4*)w_gu, (char4*)wgu8, (int)(SZ_WGU8 / 4));
  pack_i8<<<dim3(8192), dim3(256), 0, stream>>>((const int4*)w_d,  (char4*)wd8,  (int)(SZ_WD8 / 4));
  zero_u32<<<dim3(16), dim3(256), 0, stream>>>(rowmax, T_DIM);

  // 2) fused GEMM1 + silu*up + row absmax  (128x128 tile, 86x32 grid)
  gemm1_silu<<<dim3(I_DIM / 128, T_DIM / 128), dim3(256), 0, stream>>>(
      x8, wgu8, x_scale, s_wgu, y, rowmax);

  // 3) dynamic per-row quantization
  quantize_y<<<dim3((unsigned)((size_t)T_DIM * I_DIM / 4 / 256)), dim3(256), 0, stream>>>(
      y, rowmax, yq8);

  // 4) GEMM2 + scale epilogue  (128m x 256n tile, 16x32 grid)
  gemm2_scaled<<<dim3(H_DIM / 256, T_DIM / 128), dim3(256), 0, stream>>>(
      yq8, wd8, rowmax, s_wd, out);
}